// Round 8
// baseline (2774.129 us; speedup 1.0000x reference)
//
#include <hip/hip_runtime.h>
#include <hip/hip_fp16.h>

// Persistent fused GRU + value head, MI355X (gfx950).
// T=512,B=256,I=64,H=512. 256 blocks x 128 threads = 512 independent MFMA waves
// (16 batch groups x 32 weight-stationary waves). NO flags, NO atomics, NO
// barriers, NO LDS: h is exchanged through the MALL in an 8-slot ring where
// every f16 value's LSB is a step tag (tag(t)=((t>>3)&1)^1). Consumers
// speculatively load and retry until all tags match; producers store
// fire-and-forget. 4B stores are atomic -> per-dword tag check is tear-proof.
// Replay-safe: all cross-block state at the MALL; memset-0 / 0xAA poison both
// have LSB=0 = "unwritten"; stale ring slots carry the opposite tag.

#define T_  512
#define B_  256
#define I_  64
#define H_  512
#define NBG 16
#define BT  16                  // batch rows per group
#define HS  32                  // hidden units per block
#define BLOCK 128
#define NSL 32                  // value-head slices (j,wv)
#define SLOTS 8                 // h ring depth

typedef _Float16 f16;
typedef _Float16 f16x8 __attribute__((ext_vector_type(8)));
typedef float    f32x4 __attribute__((ext_vector_type(4)));
typedef unsigned int u32x2 __attribute__((ext_vector_type(2)));
typedef unsigned int u32x4 __attribute__((ext_vector_type(4)));

__device__ __forceinline__ float sigmoid_f(float x) { return 1.f / (1.f + __expf(-x)); }
__device__ __forceinline__ float tanh_f(float x) {
    float e2 = __expf(2.f * x);
    return 1.f - 2.f / (e2 + 1.f);
}

__global__ __launch_bounds__(BLOCK, 1) void gru_persistent(
    const float* __restrict__ X, const float* __restrict__ Wih,
    const float* __restrict__ Whh, const float* __restrict__ bih,
    const float* __restrict__ bhh, const float* __restrict__ vw,
    const float* __restrict__ bias, float* __restrict__ Vout,
    f16* __restrict__ hbuf, float* __restrict__ part, const int use_part)
{
    const int blk  = blockIdx.x;
    const int g    = (blk & 7) * 2 + (blk >> 7);   // batch group
    const int j    = (blk >> 3) & 15;              // hidden slice
    const int b0   = g * BT;
    const int tid  = threadIdx.x;
    const int wv   = tid >> 6;
    const int lane = tid & 63;
    const int quad = lane >> 4;
    const int mrow = lane & 15;

    // ---- stationary weights as A-operands: A[m=lane&15 -> unit][k=quad*8+e] ----
    f16x8 wh[3][16];
    f16x8 wxA[3][2];
    const int um = HS * j + wv * 16 + mrow;
    #pragma unroll
    for (int g3 = 0; g3 < 3; g3++) {
        const size_t grow = (size_t)(g3 * H_ + um);
        #pragma unroll
        for (int kt = 0; kt < 16; kt++) {
            const float* src = Whh + grow * H_ + kt * 32 + quad * 8;
            #pragma unroll
            for (int e = 0; e < 8; e++) wh[g3][kt][e] = (f16)src[e];
        }
        #pragma unroll
        for (int kt = 0; kt < 2; kt++) {
            const float* src = Wih + grow * I_ + kt * 32 + quad * 8;
            #pragma unroll
            for (int e = 0; e < 8; e++) wxA[g3][kt][e] = (f16)src[e];
        }
    }
    float b_r4[4], b_z4[4], b_ni4[4], b_nh4[4], vw4[4];
    #pragma unroll
    for (int r = 0; r < 4; r++) {
        const int ub = HS * j + wv * 16 + quad * 4 + r;
        b_r4[r]  = bih[ub] + bhh[ub];
        b_z4[r]  = bih[H_ + ub] + bhh[H_ + ub];
        b_ni4[r] = bih[2 * H_ + ub];
        b_nh4[r] = bhh[2 * H_ + ub];
        vw4[r]   = vw[ub];
    }
    float hprev[4] = {0.f, 0.f, 0.f, 0.f};   // fp32 anchor for z*h
    const int sl = j * 2 + wv;
    const float bias0 = bias[0];

    #pragma unroll 1
    for (int t = 0; t < T_; t++) {
        // ---- X_t fragments (cached; issued before the h retry loop hides them) ----
        const float* xb = X + (size_t)t * (B_ * I_) + (size_t)(b0 + mrow) * I_ + quad * 8;
        const float4 xa0 = *(const float4*)xb;
        const float4 xa1 = *(const float4*)(xb + 4);
        const float4 xc0 = *(const float4*)(xb + 32);
        const float4 xc1 = *(const float4*)(xb + 36);

        const f32x4 zero = {0.f, 0.f, 0.f, 0.f};
        f32x4 a_r = zero, a_z = zero, a_nh = zero;

        if (t > 0) {
            // ---- speculative tagged load of h_{t-1}: retry until every dword fresh ----
            const int      ls   = (t - 1) & (SLOTS - 1);
            const unsigned ltag = (((t - 1) >> 3) & 1u) ^ 1u;
            const f16* abase = hbuf + (size_t)ls * (B_ * H_)
                             + (size_t)(b0 + mrow) * H_ + quad * 8;
            f16x8 afr[16];
            for (;;) {
                asm volatile(
                    "global_load_dwordx4 %0, %16, off sc0 sc1\n\t"
                    "global_load_dwordx4 %1, %16, off offset:64 sc0 sc1\n\t"
                    "global_load_dwordx4 %2, %16, off offset:128 sc0 sc1\n\t"
                    "global_load_dwordx4 %3, %16, off offset:192 sc0 sc1\n\t"
                    "global_load_dwordx4 %4, %16, off offset:256 sc0 sc1\n\t"
                    "global_load_dwordx4 %5, %16, off offset:320 sc0 sc1\n\t"
                    "global_load_dwordx4 %6, %16, off offset:384 sc0 sc1\n\t"
                    "global_load_dwordx4 %7, %16, off offset:448 sc0 sc1\n\t"
                    "global_load_dwordx4 %8, %16, off offset:512 sc0 sc1\n\t"
                    "global_load_dwordx4 %9, %16, off offset:576 sc0 sc1\n\t"
                    "global_load_dwordx4 %10, %16, off offset:640 sc0 sc1\n\t"
                    "global_load_dwordx4 %11, %16, off offset:704 sc0 sc1\n\t"
                    "global_load_dwordx4 %12, %16, off offset:768 sc0 sc1\n\t"
                    "global_load_dwordx4 %13, %16, off offset:832 sc0 sc1\n\t"
                    "global_load_dwordx4 %14, %16, off offset:896 sc0 sc1\n\t"
                    "global_load_dwordx4 %15, %16, off offset:960 sc0 sc1\n\t"
                    "s_waitcnt vmcnt(0)"
                    : "=&v"(afr[0]), "=&v"(afr[1]), "=&v"(afr[2]), "=&v"(afr[3]),
                      "=&v"(afr[4]), "=&v"(afr[5]), "=&v"(afr[6]), "=&v"(afr[7]),
                      "=&v"(afr[8]), "=&v"(afr[9]), "=&v"(afr[10]), "=&v"(afr[11]),
                      "=&v"(afr[12]), "=&v"(afr[13]), "=&v"(afr[14]), "=&v"(afr[15])
                    : "v"(abase)
                    : "memory");
                // tag check: both f16 LSBs of every dword must equal ltag
                unsigned acc;
                if (ltag) {
                    acc = 0xFFFFFFFFu;
                    #pragma unroll
                    for (int kt = 0; kt < 16; kt++) {
                        u32x4 w = __builtin_bit_cast(u32x4, afr[kt]);
                        acc &= w.x; acc &= w.y; acc &= w.z; acc &= w.w;
                    }
                } else {
                    acc = 0u;
                    #pragma unroll
                    for (int kt = 0; kt < 16; kt++) {
                        u32x4 w = __builtin_bit_cast(u32x4, afr[kt]);
                        acc |= w.x; acc |= w.y; acc |= w.z; acc |= w.w;
                    }
                }
                const bool ok = ltag ? ((acc & 0x00010001u) == 0x00010001u)
                                     : ((acc & 0x00010001u) == 0u);
                if (__ballot(ok) == ~0ull) break;
            }
            #pragma unroll
            for (int kt = 0; kt < 16; kt++) {
                a_r  = __builtin_amdgcn_mfma_f32_16x16x32_f16(wh[0][kt], afr[kt], a_r,  0, 0, 0);
                a_z  = __builtin_amdgcn_mfma_f32_16x16x32_f16(wh[1][kt], afr[kt], a_z,  0, 0, 0);
                a_nh = __builtin_amdgcn_mfma_f32_16x16x32_f16(wh[2][kt], afr[kt], a_nh, 0, 0, 0);
            }
        }

        // ---- x projections ----
        f16x8 bx0 = {(f16)xa0.x,(f16)xa0.y,(f16)xa0.z,(f16)xa0.w,
                     (f16)xa1.x,(f16)xa1.y,(f16)xa1.z,(f16)xa1.w};
        f16x8 bx1 = {(f16)xc0.x,(f16)xc0.y,(f16)xc0.z,(f16)xc0.w,
                     (f16)xc1.x,(f16)xc1.y,(f16)xc1.z,(f16)xc1.w};
        f32x4 a_ni = __builtin_amdgcn_mfma_f32_16x16x32_f16(wxA[2][0], bx0, zero, 0, 0, 0);
        a_ni = __builtin_amdgcn_mfma_f32_16x16x32_f16(wxA[2][1], bx1, a_ni, 0, 0, 0);
        a_r  = __builtin_amdgcn_mfma_f32_16x16x32_f16(wxA[0][0], bx0, a_r,  0, 0, 0);
        a_r  = __builtin_amdgcn_mfma_f32_16x16x32_f16(wxA[0][1], bx1, a_r,  0, 0, 0);
        a_z  = __builtin_amdgcn_mfma_f32_16x16x32_f16(wxA[1][0], bx0, a_z,  0, 0, 0);
        a_z  = __builtin_amdgcn_mfma_f32_16x16x32_f16(wxA[1][1], bx1, a_z,  0, 0, 0);

        // ---- gates; pack with LSB tag; ONE fire-and-forget 8B store/lane ----
        const unsigned st_tag = ((t >> 3) & 1u) ^ 1u;
        float hn[4];
        union { unsigned short us[4]; u32x2 v; } pk;
        #pragma unroll
        for (int r = 0; r < 4; r++) {     // D: row=quad*4+r -> unit, col=mrow -> batch
            float rg = sigmoid_f(a_r[r] + b_r4[r]);
            float zg = sigmoid_f(a_z[r] + b_z4[r]);
            float ng = tanh_f(a_ni[r] + b_ni4[r] + rg * (a_nh[r] + b_nh4[r]));
            hn[r] = (1.f - zg) * ng + zg * hprev[r];
            hprev[r] = hn[r];
            f16 hv = (f16)hn[r];
            unsigned short hb = __builtin_bit_cast(unsigned short, hv);
            pk.us[r] = (unsigned short)((hb & 0xFFFEu) | st_tag);
        }
        {
            f16* hp = hbuf + (size_t)(t & (SLOTS - 1)) * (B_ * H_)
                    + (size_t)(b0 + mrow) * H_ + HS * j + wv * 16 + quad * 4;
            asm volatile("global_store_dwordx2 %0, %1, off sc0 sc1"
                         :: "v"(hp), "v"(pk.v) : "memory");
        }

        // ---- value head (off critical path) ----
        float s = hn[0] * vw4[0] + hn[1] * vw4[1] + hn[2] * vw4[2] + hn[3] * vw4[3];
        s += __shfl_xor(s, 16);
        s += __shfl_xor(s, 32);
        if (quad == 0) {
            if (use_part) part[(size_t)sl * (T_ * B_) + (size_t)t * B_ + b0 + mrow] = s;
            else atomicAdd(&Vout[(size_t)t * B_ + b0 + mrow], s + (sl == 0 ? bias0 : 0.f));
        }
    }
}

__global__ __launch_bounds__(256) void value_reduce(
    const float* __restrict__ part, const float* __restrict__ bias,
    float* __restrict__ Vout)
{
    const int i = blockIdx.x * 256 + threadIdx.x;   // i < T_*B_
    float s = bias[0];
    #pragma unroll
    for (int sl = 0; sl < NSL; sl++) s += part[(size_t)sl * (T_ * B_) + i];
    Vout[i] = s;
}

extern "C" void kernel_launch(void* const* d_in, const int* in_sizes, int n_in,
                              void* d_out, int out_size, void* d_ws, size_t ws_size,
                              hipStream_t stream) {
    const float* X    = (const float*)d_in[0];
    const float* Wih  = (const float*)d_in[1];
    const float* Whh  = (const float*)d_in[2];
    const float* bih  = (const float*)d_in[3];
    const float* bhh  = (const float*)d_in[4];
    const float* vw   = (const float*)d_in[5];
    const float* bias = (const float*)d_in[6];
    float* Vout = (float*)d_out;

    f16* hbuf = (f16*)d_ws;
    const size_t hbytes = (size_t)SLOTS * B_ * H_ * sizeof(f16);        // 2 MB
    float* part = (float*)((char*)d_ws + hbytes);
    const size_t partbytes = (size_t)NSL * T_ * B_ * sizeof(float);     // 16.8 MB
    const int use_part = (ws_size >= hbytes + partbytes) ? 1 : 0;

    hipMemsetAsync(hbuf, 0, hbytes, stream);   // LSB=0 everywhere = "unwritten"
    if (!use_part)
        hipMemsetAsync(d_out, 0, (size_t)out_size * sizeof(float), stream);

    gru_persistent<<<256, BLOCK, 0, stream>>>(X, Wih, Whh, bih, bhh, vw, bias,
                                              Vout, hbuf, part, use_part);
    if (use_part)
        value_reduce<<<(T_ * B_) / 256, 256, 0, stream>>>(part, bias, Vout);
}

// Round 10
// 1877.602 us; speedup vs baseline: 1.4775x; 1.4775x over previous
//
#include <hip/hip_runtime.h>
#include <hip/hip_fp16.h>

// Persistent fused GRU + value head, MI355X (gfx950).
// T=512,B=256,I=64,H=512. 256 blocks x 128 threads = 512 autonomous MFMA waves
// (16 batch groups x 16 slices x 2 waves). NO barriers, NO LDS, NO service wave,
// NO atomics/RMWs, NO producer drain:
//   discovery: per-wave flag words at the MALL (ballot poll, R7-proven) so
//              consumers never touch h lines before they are written (avoids
//              R8's cold-miss DRAM fills);
//   ordering:  every stored f16 carries a step tag in its LSB (R8-proven
//              precision-neutral); producer fires h stores + flag with no
//              vmcnt drain; if the flag wins the race the consumer's tag
//              check fails and it reloads (rare).
// All cross-block state agent-scope at the MALL — replay-safe (memset zeros:
// LSB=0 = stale, flags=0). XCD-local experiments abandoned (R5/R9 infra).

#define T_  512
#define B_  256
#define I_  64
#define H_  512
#define NBG 16
#define BT  16                  // batch rows per group
#define HS  32                  // hidden units per block
#define BLOCK 128
#define NSL 32                  // value-head slices (j,wv)
#define SLOTS 8                 // h ring depth
#define FLAG_STRIDE 32          // dwords: 128 B between flag words
#define TAGM 0x00010001u

typedef _Float16 f16;
typedef _Float16 f16x8 __attribute__((ext_vector_type(8)));
typedef float    f32x4 __attribute__((ext_vector_type(4)));
typedef unsigned int u32x2 __attribute__((ext_vector_type(2)));
typedef unsigned int u32x4 __attribute__((ext_vector_type(4)));

__device__ __forceinline__ float sigmoid_f(float x) { return 1.f / (1.f + __expf(-x)); }
__device__ __forceinline__ float tanh_f(float x) {
    float e2 = __expf(2.f * x);
    return 1.f - 2.f / (e2 + 1.f);
}

// h-only reload (retry path): 16 x 16B, full drain.
#define H_RELOAD()                                                             \
    asm volatile(                                                              \
        "global_load_dwordx4 %0, %16, off sc0 sc1\n\t"                         \
        "global_load_dwordx4 %1, %16, off offset:64 sc0 sc1\n\t"               \
        "global_load_dwordx4 %2, %16, off offset:128 sc0 sc1\n\t"              \
        "global_load_dwordx4 %3, %16, off offset:192 sc0 sc1\n\t"              \
        "global_load_dwordx4 %4, %16, off offset:256 sc0 sc1\n\t"              \
        "global_load_dwordx4 %5, %16, off offset:320 sc0 sc1\n\t"              \
        "global_load_dwordx4 %6, %16, off offset:384 sc0 sc1\n\t"              \
        "global_load_dwordx4 %7, %16, off offset:448 sc0 sc1\n\t"              \
        "global_load_dwordx4 %8, %16, off offset:512 sc0 sc1\n\t"              \
        "global_load_dwordx4 %9, %16, off offset:576 sc0 sc1\n\t"              \
        "global_load_dwordx4 %10, %16, off offset:640 sc0 sc1\n\t"             \
        "global_load_dwordx4 %11, %16, off offset:704 sc0 sc1\n\t"             \
        "global_load_dwordx4 %12, %16, off offset:768 sc0 sc1\n\t"             \
        "global_load_dwordx4 %13, %16, off offset:832 sc0 sc1\n\t"             \
        "global_load_dwordx4 %14, %16, off offset:896 sc0 sc1\n\t"             \
        "global_load_dwordx4 %15, %16, off offset:960 sc0 sc1\n\t"             \
        "s_waitcnt vmcnt(0)"                                                   \
        : "=&v"(afr[0]), "=&v"(afr[1]), "=&v"(afr[2]), "=&v"(afr[3]),          \
          "=&v"(afr[4]), "=&v"(afr[5]), "=&v"(afr[6]), "=&v"(afr[7]),          \
          "=&v"(afr[8]), "=&v"(afr[9]), "=&v"(afr[10]), "=&v"(afr[11]),        \
          "=&v"(afr[12]), "=&v"(afr[13]), "=&v"(afr[14]), "=&v"(afr[15])       \
        : "v"(abase)                                                           \
        : "memory")

__global__ __launch_bounds__(BLOCK, 1) void gru_persistent(
    const float* __restrict__ X, const float* __restrict__ Wih,
    const float* __restrict__ Whh, const float* __restrict__ bih,
    const float* __restrict__ bhh, const float* __restrict__ vw,
    const float* __restrict__ bias, float* __restrict__ Vout,
    f16* __restrict__ hbuf, unsigned int* __restrict__ flags,
    float* __restrict__ part, const int use_part)
{
    const int blk  = blockIdx.x;
    const int g    = (blk & 7) * 2 + (blk >> 7);   // batch group
    const int j    = (blk >> 3) & 15;              // hidden slice
    const int b0   = g * BT;
    const int tid  = threadIdx.x;
    const int wv   = tid >> 6;
    const int lane = tid & 63;
    const int quad = lane >> 4;
    const int mrow = lane & 15;

    // ---- stationary weights as A-operands: A[m=lane&15 -> unit][k=quad*8+e] ----
    f16x8 wh[3][16];
    f16x8 wxA[3][2];
    const int um = HS * j + wv * 16 + mrow;
    #pragma unroll
    for (int g3 = 0; g3 < 3; g3++) {
        const size_t grow = (size_t)(g3 * H_ + um);
        #pragma unroll
        for (int kt = 0; kt < 16; kt++) {
            const float* src = Whh + grow * H_ + kt * 32 + quad * 8;
            #pragma unroll
            for (int e = 0; e < 8; e++) wh[g3][kt][e] = (f16)src[e];
        }
        #pragma unroll
        for (int kt = 0; kt < 2; kt++) {
            const float* src = Wih + grow * I_ + kt * 32 + quad * 8;
            #pragma unroll
            for (int e = 0; e < 8; e++) wxA[g3][kt][e] = (f16)src[e];
        }
    }
    float b_r4[4], b_z4[4], b_ni4[4], b_nh4[4], vw4[4];
    #pragma unroll
    for (int r = 0; r < 4; r++) {
        const int ub = HS * j + wv * 16 + quad * 4 + r;
        b_r4[r]  = bih[ub] + bhh[ub];
        b_z4[r]  = bih[H_ + ub] + bhh[H_ + ub];
        b_ni4[r] = bih[2 * H_ + ub];
        b_nh4[r] = bhh[2 * H_ + ub];
        vw4[r]   = vw[ub];
    }
    float hprev[4] = {0.f, 0.f, 0.f, 0.f};   // fp32 anchor for z*h
    unsigned int* gflags = flags + (size_t)g * (32 * FLAG_STRIDE);
    unsigned int* myflag = gflags + (j * 2 + wv) * FLAG_STRIDE;
    const int sl = j * 2 + wv;
    const float bias0 = bias[0];

    #pragma unroll 1
    for (int t = 0; t < T_; t++) {
        const f32x4 zero = {0.f, 0.f, 0.f, 0.f};
        f32x4 a_r = zero, a_z = zero, a_nh = zero;
        f32x4 xv0, xv1, xv2, xv3;
        const float* xb = X + (size_t)t * (B_ * I_) + (size_t)(b0 + mrow) * I_ + quad * 8;

        if (t > 0) {
            // ---- 1. flag discovery: ballot over 32 peer flags (R7 mechanism) ----
            const unsigned target = (unsigned)t;
            for (;;) {
                unsigned v = target;
                if (lane < 32) {
                    const unsigned int* fp = gflags + lane * FLAG_STRIDE;
                    asm volatile("global_load_dword %0, %1, off sc0 sc1\n\t"
                                 "s_waitcnt vmcnt(0)"
                                 : "=v"(v) : "v"(fp) : "memory");
                }
                if (__ballot(v >= target) == ~0ull) break;
            }

            // ---- 2. h_{t-1} (16x16B) + X_t (4x16B) in one issue burst; drain h only ----
            const int      ls   = (t - 1) & (SLOTS - 1);
            const unsigned ltag = (((t - 1) >> 3) & 1u) ^ 1u;
            const f16* abase = hbuf + (size_t)ls * (B_ * H_)
                             + (size_t)(b0 + mrow) * H_ + quad * 8;
            f16x8 afr[16];
            asm volatile(
                "global_load_dwordx4 %0, %20, off sc0 sc1\n\t"
                "global_load_dwordx4 %1, %20, off offset:64 sc0 sc1\n\t"
                "global_load_dwordx4 %2, %20, off offset:128 sc0 sc1\n\t"
                "global_load_dwordx4 %3, %20, off offset:192 sc0 sc1\n\t"
                "global_load_dwordx4 %4, %20, off offset:256 sc0 sc1\n\t"
                "global_load_dwordx4 %5, %20, off offset:320 sc0 sc1\n\t"
                "global_load_dwordx4 %6, %20, off offset:384 sc0 sc1\n\t"
                "global_load_dwordx4 %7, %20, off offset:448 sc0 sc1\n\t"
                "global_load_dwordx4 %8, %20, off offset:512 sc0 sc1\n\t"
                "global_load_dwordx4 %9, %20, off offset:576 sc0 sc1\n\t"
                "global_load_dwordx4 %10, %20, off offset:640 sc0 sc1\n\t"
                "global_load_dwordx4 %11, %20, off offset:704 sc0 sc1\n\t"
                "global_load_dwordx4 %12, %20, off offset:768 sc0 sc1\n\t"
                "global_load_dwordx4 %13, %20, off offset:832 sc0 sc1\n\t"
                "global_load_dwordx4 %14, %20, off offset:896 sc0 sc1\n\t"
                "global_load_dwordx4 %15, %20, off offset:960 sc0 sc1\n\t"
                "global_load_dwordx4 %16, %21, off\n\t"
                "global_load_dwordx4 %17, %21, off offset:16\n\t"
                "global_load_dwordx4 %18, %21, off offset:128\n\t"
                "global_load_dwordx4 %19, %21, off offset:144\n\t"
                "s_waitcnt vmcnt(4)"               // oldest 16 (= all h) done; X in flight
                : "=&v"(afr[0]), "=&v"(afr[1]), "=&v"(afr[2]), "=&v"(afr[3]),
                  "=&v"(afr[4]), "=&v"(afr[5]), "=&v"(afr[6]), "=&v"(afr[7]),
                  "=&v"(afr[8]), "=&v"(afr[9]), "=&v"(afr[10]), "=&v"(afr[11]),
                  "=&v"(afr[12]), "=&v"(afr[13]), "=&v"(afr[14]), "=&v"(afr[15]),
                  "=&v"(xv0), "=&v"(xv1), "=&v"(xv2), "=&v"(xv3)
                : "v"(abase), "v"(xb)
                : "memory");

            // ---- 3. tag validation (flag may have beaten the data; reload if so) ----
            for (;;) {
                unsigned accA = 0xFFFFFFFFu, accO = 0u;
                #pragma unroll
                for (int kt = 0; kt < 16; kt++) {
                    u32x4 w = __builtin_bit_cast(u32x4, afr[kt]);
                    accA &= w.x; accA &= w.y; accA &= w.z; accA &= w.w;
                    accO |= w.x; accO |= w.y; accO |= w.z; accO |= w.w;
                }
                const bool ok = ltag ? ((accA & TAGM) == TAGM)
                                     : ((accO & TAGM) == 0u);
                if (__ballot(ok) == ~0ull) break;
                H_RELOAD();
            }

            // ---- 4. 48 h-MFMAs (X latency hides under these) ----
            #pragma unroll
            for (int kt = 0; kt < 16; kt++) {
                a_r  = __builtin_amdgcn_mfma_f32_16x16x32_f16(wh[0][kt], afr[kt], a_r,  0, 0, 0);
                a_z  = __builtin_amdgcn_mfma_f32_16x16x32_f16(wh[1][kt], afr[kt], a_z,  0, 0, 0);
                a_nh = __builtin_amdgcn_mfma_f32_16x16x32_f16(wh[2][kt], afr[kt], a_nh, 0, 0, 0);
            }
            // X regs valid only after full drain; tie xv* through the waitcnt
            asm volatile("s_waitcnt vmcnt(0)"
                         : "+v"(xv0), "+v"(xv1), "+v"(xv2), "+v"(xv3) :: "memory");
        } else {
            xv0 = *(const f32x4*)xb;
            xv1 = *(const f32x4*)(xb + 4);
            xv2 = *(const f32x4*)(xb + 32);
            xv3 = *(const f32x4*)(xb + 36);
        }

        // ---- 5. x-projections ----
        f16x8 bx0 = {(f16)xv0[0],(f16)xv0[1],(f16)xv0[2],(f16)xv0[3],
                     (f16)xv1[0],(f16)xv1[1],(f16)xv1[2],(f16)xv1[3]};
        f16x8 bx1 = {(f16)xv2[0],(f16)xv2[1],(f16)xv2[2],(f16)xv2[3],
                     (f16)xv3[0],(f16)xv3[1],(f16)xv3[2],(f16)xv3[3]};
        f32x4 a_ni = __builtin_amdgcn_mfma_f32_16x16x32_f16(wxA[2][0], bx0, zero, 0, 0, 0);
        a_ni = __builtin_amdgcn_mfma_f32_16x16x32_f16(wxA[2][1], bx1, a_ni, 0, 0, 0);
        a_r  = __builtin_amdgcn_mfma_f32_16x16x32_f16(wxA[0][0], bx0, a_r,  0, 0, 0);
        a_r  = __builtin_amdgcn_mfma_f32_16x16x32_f16(wxA[0][1], bx1, a_r,  0, 0, 0);
        a_z  = __builtin_amdgcn_mfma_f32_16x16x32_f16(wxA[1][0], bx0, a_z,  0, 0, 0);
        a_z  = __builtin_amdgcn_mfma_f32_16x16x32_f16(wxA[1][1], bx1, a_z,  0, 0, 0);

        // ---- 6. gates; pack tagged h; fire stores + flag with NO drain ----
        const unsigned st_tag = ((t >> 3) & 1u) ^ 1u;
        float hn[4];
        union { unsigned short us[4]; u32x2 v; } pk;
        #pragma unroll
        for (int r = 0; r < 4; r++) {     // D: row=quad*4+r -> unit, col=mrow -> batch
            float rg = sigmoid_f(a_r[r] + b_r4[r]);
            float zg = sigmoid_f(a_z[r] + b_z4[r]);
            float ng = tanh_f(a_ni[r] + b_ni4[r] + rg * (a_nh[r] + b_nh4[r]));
            hn[r] = (1.f - zg) * ng + zg * hprev[r];
            hprev[r] = hn[r];
            f16 hv = (f16)hn[r];
            unsigned short hb = __builtin_bit_cast(unsigned short, hv);
            pk.us[r] = (unsigned short)((hb & 0xFFFEu) | st_tag);
        }
        {
            f16* hp = hbuf + (size_t)(t & (SLOTS - 1)) * (B_ * H_)
                    + (size_t)(b0 + mrow) * H_ + HS * j + wv * 16 + quad * 4;
            asm volatile("global_store_dwordx2 %0, %1, off sc0 sc1"
                         :: "v"(hp), "v"(pk.v) : "memory");
        }
        if (lane == 0) {
            const unsigned fv = (unsigned)(t + 1);
            asm volatile("global_store_dword %0, %1, off sc0 sc1"
                         :: "v"(myflag), "v"(fv) : "memory");
        }

        // ---- 7. value head (off critical path) ----
        float s = hn[0] * vw4[0] + hn[1] * vw4[1] + hn[2] * vw4[2] + hn[3] * vw4[3];
        s += __shfl_xor(s, 16);
        s += __shfl_xor(s, 32);
        if (quad == 0) {
            if (use_part) part[(size_t)sl * (T_ * B_) + (size_t)t * B_ + b0 + mrow] = s;
            else atomicAdd(&Vout[(size_t)t * B_ + b0 + mrow], s + (sl == 0 ? bias0 : 0.f));
        }
    }
}

__global__ __launch_bounds__(256) void value_reduce(
    const float* __restrict__ part, const float* __restrict__ bias,
    float* __restrict__ Vout)
{
    const int i = blockIdx.x * 256 + threadIdx.x;   // i < T_*B_
    float s = bias[0];
    #pragma unroll
    for (int sl = 0; sl < NSL; sl++) s += part[(size_t)sl * (T_ * B_) + i];
    Vout[i] = s;
}

extern "C" void kernel_launch(void* const* d_in, const int* in_sizes, int n_in,
                              void* d_out, int out_size, void* d_ws, size_t ws_size,
                              hipStream_t stream) {
    const float* X    = (const float*)d_in[0];
    const float* Wih  = (const float*)d_in[1];
    const float* Whh  = (const float*)d_in[2];
    const float* bih  = (const float*)d_in[3];
    const float* bhh  = (const float*)d_in[4];
    const float* vw   = (const float*)d_in[5];
    const float* bias = (const float*)d_in[6];
    float* Vout = (float*)d_out;

    f16* hbuf = (f16*)d_ws;
    const size_t hbytes    = (size_t)SLOTS * B_ * H_ * sizeof(f16);               // 2 MB
    const size_t flagbytes = (size_t)NBG * 32 * FLAG_STRIDE * sizeof(unsigned);   // 64 KB
    unsigned int* flags = (unsigned int*)((char*)d_ws + hbytes);
    float* part = (float*)((char*)d_ws + hbytes + flagbytes);
    const size_t partbytes = (size_t)NSL * T_ * B_ * sizeof(float);               // 16.8 MB
    const int use_part = (ws_size >= hbytes + flagbytes + partbytes) ? 1 : 0;

    hipMemsetAsync(d_ws, 0, hbytes + flagbytes, stream);   // tags stale, flags 0
    if (!use_part)
        hipMemsetAsync(d_out, 0, (size_t)out_size * sizeof(float), stream);

    gru_persistent<<<256, BLOCK, 0, stream>>>(X, Wih, Whh, bih, bhh, vw, bias,
                                              Vout, hbuf, flags, part, use_part);
    if (use_part)
        value_reduce<<<(T_ * B_) / 256, 256, 0, stream>>>(part, bias, Vout);
}